// Round 15
// baseline (401.563 us; speedup 1.0000x reference)
//
#include <hip/hip_runtime.h>
#include <hip/hip_bf16.h>

#define NNODE 50000
#define DIM   256
#define EDGES 400000
#define NET   4
#define NTOT  (NET * NNODE)          // 200000
#define BSH   7
#define NBUCK ((NTOT + 127) >> BSH)  // 1563
#define EPB2  8192                   // edges per chunk
#define CPE   49                     // chunks per etype (49*8192 >= 400000)
#define NBLKT (CPE * NET)            // 196 chunk-blocks total
#define NSCAN (NBUCK * NBLKT)        // 306348

#define AS1 __attribute__((address_space(1)))
#define AS3 __attribute__((address_space(3)))

typedef __attribute__((ext_vector_type(8))) __bf16 bf16x8;
typedef __attribute__((ext_vector_type(4))) float f32x4;
typedef __attribute__((ext_vector_type(4))) unsigned short u16x4;
typedef __attribute__((ext_vector_type(8))) unsigned short u16x8;

__device__ __forceinline__ float bf2f(unsigned short u) {
  unsigned int x = ((unsigned int)u) << 16;
  return __builtin_bit_cast(float, x);
}
__device__ __forceinline__ unsigned short f2bf(float f) {
  __hip_bfloat16 h = __float2bfloat16(f);   // RTNE
  return __builtin_bit_cast(unsigned short, h);
}

__global__ void conv_f32_bf16(const float* __restrict__ in, unsigned short* __restrict__ out, int n4) {
  int i = blockIdx.x * blockDim.x + threadIdx.x;
  if (i >= n4) return;
  f32x4 v = reinterpret_cast<const f32x4*>(in)[i];
  u16x4 o;
  o[0] = f2bf(v[0]); o[1] = f2bf(v[1]); o[2] = f2bf(v[2]); o[3] = f2bf(v[3]);
  reinterpret_cast<u16x4*>(out)[i] = o;
}

// Stacked-K weights in BK=32-chunk-major PRE-SWIZZLED layout (proven rounds 13/14):
// logical (row n, k<512) -> T[ck*8192 + n*32 + ((kg^(n&3))<<3) + j]  (ushort units),
// ck = k>>5 (A-half: slabs 0..7) / 8+(k>>5) (B-half: slabs 8..15), kg=(k>>3)&3,
// j=k&7. Each slab is a contiguous 16KB chunk (fully sequential staging); the
// kg-XOR pre-swizzle makes ds_read_b128 B-frags bank-friendly with a LINEAR LDS
// image (rule 21: swizzle source, linear dest).
__global__ void conv_wT32(const float* __restrict__ a0, const float* __restrict__ b0,
                          const float* __restrict__ a1, const float* __restrict__ b1,
                          const float* __restrict__ a2, const float* __restrict__ b2,
                          unsigned short* __restrict__ t0, unsigned short* __restrict__ t1,
                          unsigned short* __restrict__ t2) {
  int m = blockIdx.y;
  const float* A = (m == 0) ? a0 : (m == 1) ? a1 : a2;
  const float* B = (m == 0) ? b0 : (m == 1) ? b1 : b2;
  unsigned short* T = (m == 0) ? t0 : (m == 1) ? t1 : t2;
  int n = blockIdx.x, k = threadIdx.x;   // 256 threads, k in [0,256)
  int kg = (k >> 3) & 3, j = k & 7;
  int sw = ((kg ^ (n & 3)) << 3) + j;
  T[(k >> 5) * 8192 + n * 32 + sw]       = f2bf(A[k * 256 + n]);   // A-half: ck 0..7
  T[(8 + (k >> 5)) * 8192 + n * 32 + sw] = f2bf(B[k * 256 + n]);   // B-half: ck 8..15
}

__global__ void fill_f32(float* __restrict__ p, float v, int n) {
  int i = blockIdx.x * blockDim.x + threadIdx.x;
  if (i < n) p[i] = v;
}

// ---- multi-split CSR build: no per-edge global atomics (proven rounds 3-14) ----
__global__ void hist_ms(const int* __restrict__ d0, const int* __restrict__ d1,
                        const int* __restrict__ d2, const int* __restrict__ d3,
                        int* __restrict__ cnt) {
  __shared__ int h[NBUCK];
  for (int i = threadIdx.x; i < NBUCK; i += 256) h[i] = 0;
  __syncthreads();
  int t = blockIdx.y, cx = blockIdx.x;
  const int* dp = (t == 0) ? d0 : (t == 1) ? d1 : (t == 2) ? d2 : d3;
  int base = cx * EPB2;
  int lim = base + EPB2; if (lim > EDGES) lim = EDGES;
  for (int i = base + threadIdx.x; i < lim; i += 256)
    atomicAdd(&h[(t * NNODE + dp[i]) >> BSH], 1);
  __syncthreads();
  int blk = t * CPE + cx;
  for (int i = threadIdx.x; i < NBUCK; i += 256)
    cnt[i * NBLKT + blk] = h[i];
}

__global__ void scan_p1(const int* __restrict__ data, int* __restrict__ bsum, int n) {
  __shared__ int red[256];
  int base = blockIdx.x * 4096;
  int s = 0;
  #pragma unroll
  for (int j = 0; j < 16; j++) {
    int idx = base + j * 256 + threadIdx.x;
    s += (idx < n) ? data[idx] : 0;
  }
  red[threadIdx.x] = s;
  __syncthreads();
  for (int o = 128; o > 0; o >>= 1) {
    if (threadIdx.x < o) red[threadIdx.x] += red[threadIdx.x + o];
    __syncthreads();
  }
  if (threadIdx.x == 0) bsum[blockIdx.x] = red[0];
}

__global__ void scan_p2(int* __restrict__ bsum, int nb, int* __restrict__ off, int nscan,
                        int* __restrict__ S) {
  __shared__ int sh[128];
  int tid = threadIdx.x;
  int v = (tid < nb) ? bsum[tid] : 0;
  sh[tid] = v;
  __syncthreads();
  for (int o = 1; o < 128; o <<= 1) {
    int a = (tid >= o) ? sh[tid - o] : 0;
    __syncthreads();
    sh[tid] += a;
    __syncthreads();
  }
  if (tid < nb) bsum[tid] = sh[tid] - v;   // exclusive block bases
  if (tid == 0) { off[nscan] = sh[127]; S[NTOT] = sh[127]; }
}

__global__ void scan_p3(int* __restrict__ data, const int* __restrict__ bsum, int n) {
  __shared__ int sh[256];
  int tid = threadIdx.x;
  int base = blockIdx.x * 4096 + tid * 16;
  int vals[16];
  int s = 0;
  #pragma unroll
  for (int j = 0; j < 16; j++) {
    vals[j] = (base + j < n) ? data[base + j] : 0;
    s += vals[j];
  }
  sh[tid] = s;
  __syncthreads();
  for (int o = 1; o < 256; o <<= 1) {
    int a = (tid >= o) ? sh[tid - o] : 0;
    __syncthreads();
    sh[tid] += a;
    __syncthreads();
  }
  int run = bsum[blockIdx.x] + sh[tid] - s;
  #pragma unroll
  for (int j = 0; j < 16; j++) {
    if (base + j < n) { data[base + j] = run; run += vals[j]; }
  }
}

__global__ void scatter_ms(const int* __restrict__ s0, const int* __restrict__ s1,
                           const int* __restrict__ s2, const int* __restrict__ s3,
                           const int* __restrict__ d0, const int* __restrict__ d1,
                           const int* __restrict__ d2, const int* __restrict__ d3,
                           const int* __restrict__ off, unsigned int* __restrict__ pairs) {
  __shared__ int cur[NBUCK];
  int t = blockIdx.y, cx = blockIdx.x;
  int blk = t * CPE + cx;
  for (int i = threadIdx.x; i < NBUCK; i += 256)
    cur[i] = off[i * NBLKT + blk];
  __syncthreads();
  const int* sp = (t == 0) ? s0 : (t == 1) ? s1 : (t == 2) ? s2 : s3;
  const int* dp = (t == 0) ? d0 : (t == 1) ? d1 : (t == 2) ? d2 : d3;
  int base = cx * EPB2;
  int lim = base + EPB2; if (lim > EDGES) lim = EDGES;
  for (int i = base + threadIdx.x; i < lim; i += 256) {
    int key = t * NNODE + dp[i];
    int slot = atomicAdd(&cur[key >> BSH], 1);
    pairs[slot] = ((unsigned int)(key & 127) << 16) | (unsigned int)sp[i];
  }
}

__global__ void bucket_final(const int* __restrict__ off, const unsigned int* __restrict__ pairs,
                             int* __restrict__ S, int* __restrict__ srcs) {
  __shared__ int lcnt[128];
  __shared__ int loff[128];
  int b = blockIdx.x;
  int tid = threadIdx.x;
  int beg = off[b * NBLKT], end = off[(b + 1) * NBLKT];
  if (tid < 128) lcnt[tid] = 0;
  __syncthreads();
  for (int e = beg + tid; e < end; e += 256)
    atomicAdd(&lcnt[pairs[e] >> 16], 1);
  __syncthreads();
  int c = (tid < 128) ? lcnt[tid] : 0;
  if (tid < 128) loff[tid] = c;
  __syncthreads();
  for (int o = 1; o < 128; o <<= 1) {
    int a = (tid < 128 && tid >= o) ? loff[tid - o] : 0;
    __syncthreads();
    if (tid < 128) loff[tid] += a;
    __syncthreads();
  }
  if (tid < 128) {
    int ex = loff[tid] - c;
    int key = (b << BSH) + tid;
    if (key < NTOT) S[key] = beg + ex;
    lcnt[tid] = ex;                   // running cursor
  }
  __syncthreads();
  for (int e = beg + tid; e < end; e += 256) {
    unsigned int p = pairs[e];
    int lk = p >> 16;
    int slot = beg + atomicAdd(&lcnt[lk], 1);
    srcs[slot] = (int)(p & 0xFFFFu);
  }
}

// ---- aggregation: mean of src features per (etype, dst). Two etypes fused.
// Output written in the GEMM's BK=32 slab-major pre-swizzled layout:
// elem k of row d -> slab (k>>5), off d*32 + (((k>>3)&3 ^ (d&3))<<3) + (k&7).
#define ACC8(V)                                             \
  { _Pragma("unroll")                                       \
    for (int j = 0; j < 8; j++) acc[j] += bf2f((V)[j]); }

__device__ __forceinline__ void agg_loop(const int* __restrict__ srcs, int e0, int e1,
                                         int half, int l5,
                                         const unsigned short* __restrict__ feat, float* acc) {
  int e = e0 + half;
  u16x8 z = {};
  #define LDK(K) ((e + 2*(K) < e1)                                                    \
      ? *reinterpret_cast<const u16x8*>(feat + (size_t)srcs[e + 2*(K)] * 256 + l5 * 8) \
      : z)
  u16x8 v0 = LDK(0), v1 = LDK(1), v2 = LDK(2), v3 = LDK(3);
  while (e + 8 < e1) {
    u16x8 c0 = v0, c1 = v1, c2 = v2, c3 = v3;
    e += 8;
    v0 = LDK(0); v1 = LDK(1); v2 = LDK(2); v3 = LDK(3);
    ACC8(c0); ACC8(c1); ACC8(c2); ACC8(c3);
  }
  ACC8(v0); ACC8(v1); ACC8(v2); ACC8(v3);   // masked-out slots are zero
  #undef LDK
}

__global__ __launch_bounds__(256) void agg_pair(
    const int* __restrict__ S, const int* __restrict__ srcs,
    const unsigned short* __restrict__ featA, int etA, unsigned short* __restrict__ outA,
    const unsigned short* __restrict__ featB, int etB, unsigned short* __restrict__ outB)
{
  int d = blockIdx.x * 4 + (threadIdx.x >> 6);
  int lane = threadIdx.x & 63;
  int half = lane >> 5, l5 = lane & 31;
  // BK=32 slab-major pre-swizzled output position: lane holds k = l5*8..l5*8+7
  // -> slab l5>>2, seg (l5&3)^(d&3); in ushort units (row = 32 elems).
  size_t obase = ((size_t)(l5 >> 2) * NNODE + d) * 32 + (size_t)(((l5 & 3) ^ (d & 3)) << 3);

  int gA = etA * NNODE + d;
  int a0 = S[gA], a1 = S[gA + 1];
  int gB = etB * NNODE + d;
  int b0 = S[gB], b1 = S[gB + 1];

  {
    float acc[8] = {0,0,0,0,0,0,0,0};
    agg_loop(srcs, a0, a1, half, l5, featA, acc);
    #pragma unroll
    for (int j = 0; j < 8; j++) acc[j] += __shfl_xor(acc[j], 32);
    float dA = (float)(a1 - a0); if (dA < 1.f) dA = 1.f;
    float invA = 1.f / dA;
    if (half == 0) {
      u16x8 o;
      #pragma unroll
      for (int j = 0; j < 8; j++) o[j] = f2bf(acc[j] * invA);
      *reinterpret_cast<u16x8*>(outA + obase) = o;
    }
  }
  {
    float acc[8] = {0,0,0,0,0,0,0,0};
    agg_loop(srcs, b0, b1, half, l5, featB, acc);
    #pragma unroll
    for (int j = 0; j < 8; j++) acc[j] += __shfl_xor(acc[j], 32);
    float dB = (float)(b1 - b0); if (dB < 1.f) dB = 1.f;
    float invB = 1.f / dB;
    if (half == 1) {
      u16x8 o;
      #pragma unroll
      for (int j = 0; j < 8; j++) o[j] = f2bf(acc[j] * invB);
      *reinterpret_cast<u16x8*>(outB + obase) = o;
    }
  }
}

// ---- stacked-K GEMM v11: BK=64 sync periods, single 40KB buffer, 4 blocks/CU.
// Combines the two measured-positive levers: 4 blocks/CU (round 14, +15%) and
// 2x MFMA per barrier pair (16 barrier pairs -> 8). No within-block pipeline at
// all: stage -> vmcnt(0) -> barrier -> compute(2 slabs) -> barrier. Latency is
// hidden purely by the 4 co-resident blocks (16 waves/CU). All staging/swizzle/
// fragment code identical to the passing v10 (BK=32 slab layout; one chunk =
// two consecutive slabs; B-slabs contiguous 32KB).
// MODE 0: leaky_relu + bf16 row-major out. MODE 1: f32 row-major out.
template<int MODE>
__global__ __launch_bounds__(256, 4) void gemm512(
    const unsigned short* __restrict__ A0, const unsigned short* __restrict__ A1,
    const unsigned short* __restrict__ WTb,
    const float* __restrict__ bA, const float* __restrict__ bB,
    const int* __restrict__ S, int etA, int etB,
    void* __restrict__ outp, int M)
{
  __shared__ char lds[40960];        // A slabs 2x4KB | B slabs 2x16KB
  int tid = threadIdx.x;
  int m0 = blockIdx.x * 64;
  int wave = tid >> 6, lane = tid & 63;
  int wr = wave >> 1, wc = wave & 1;
  int lrow = lane & 15, kgrp = lane >> 4;

  f32x4 acc[2][8];
  #pragma unroll
  for (int a = 0; a < 2; a++)
    #pragma unroll
    for (int b = 0; b < 8; b++) acc[a][b] = (f32x4){0.f, 0.f, 0.f, 0.f};

  // stage chunk ck = slabs {2ck, 2ck+1}: B 32KB contiguous, A 2x4KB slabs
  auto stage = [&](int ck) {
    const char* wsrc = (const char*)WTb + (size_t)ck * 32768 + tid * 16;
    #pragma unroll
    for (int iss = 0; iss < 8; iss++)
      __builtin_amdgcn_global_load_lds(
          (const AS1 unsigned int*)(const void*)(wsrc + iss * 4096),
          (AS3 unsigned int*)(void*)(lds + 8192 + iss * 4096 + tid * 16), 16, 0, 0);
    #pragma unroll
    for (int s = 0; s < 2; s++) {
      int ks32 = 2 * ck + s;
      const char* asrc = (const char*)((ks32 < 8) ? A0 : A1) +
          (size_t)(ks32 & 7) * NNODE * 64 + (size_t)m0 * 64 + tid * 16;
      __builtin_amdgcn_global_load_lds(
          (const AS1 unsigned int*)(const void*)asrc,
          (AS3 unsigned int*)(void*)(lds + s * 4096 + tid * 16), 16, 0, 0);
    }
  };

  auto compute = [&]() {
    #pragma unroll
    for (int s = 0; s < 2; s++) {
      const char* abase = lds + s * 4096;
      const char* bbase = lds + 8192 + s * 16384;
      bf16x8 a[2];
      #pragma unroll
      for (int mb = 0; mb < 2; mb++) {
        int r = 32 * wr + 16 * mb + lrow;
        a[mb] = *reinterpret_cast<const bf16x8*>(abase + r * 64 + ((kgrp ^ (r & 3)) << 4));
      }
      #pragma unroll
      for (int nb = 0; nb < 8; nb++) {
        int n = 128 * wc + 16 * nb + lrow;
        bf16x8 b = *reinterpret_cast<const bf16x8*>(bbase + n * 64 + ((kgrp ^ (n & 3)) << 4));
        acc[0][nb] = __builtin_amdgcn_mfma_f32_16x16x32_bf16(a[0], b, acc[0][nb], 0, 0, 0);
        acc[1][nb] = __builtin_amdgcn_mfma_f32_16x16x32_bf16(a[1], b, acc[1][nb], 0, 0, 0);
      }
    }
  };

  for (int ck = 0; ck < 8; ck++) {
    stage(ck);
    asm volatile("s_waitcnt vmcnt(0)" ::: "memory");  // chunk fully landed
    asm volatile("s_barrier" ::: "memory");           // visible to all waves
    compute();
    if (ck < 7)
      asm volatile("s_barrier" ::: "memory");         // all readers done before overwrite
  }

  // C/D layout: col = lane&15, row = (lane>>4)*4 + reg  [verified m89/m91]
  #pragma unroll
  for (int mb = 0; mb < 2; mb++) {
    #pragma unroll
    for (int r = 0; r < 4; r++) {
      int row = m0 + 32 * wr + 16 * mb + kgrp * 4 + r;
      if (row >= M) continue;
      int gA = etA * NNODE + row, gB = etB * NNODE + row;
      bool hA = S[gA + 1] > S[gA];   // deg>0: bias enters only via messages
      bool hB = S[gB + 1] > S[gB];
      #pragma unroll
      for (int nb = 0; nb < 8; nb++) {
        int col = 128 * wc + 16 * nb + lrow;
        float bias = (hA ? bA[col] : 0.f) + (hB ? bB[col] : 0.f);
        float v = acc[mb][nb][r] + bias;
        if (MODE == 0) {
          v = (v > 0.f) ? v : 0.01f * v;
          ((unsigned short*)outp)[(size_t)row * 256 + col] = f2bf(v);
        } else {
          ((float*)outp)[(size_t)row * 256 + col] = v;
        }
      }
    }
  }
}

extern "C" void kernel_launch(void* const* d_in, const int* in_sizes, int n_in,
                              void* d_out, int out_size, void* d_ws, size_t ws_size,
                              hipStream_t stream) {
  (void)in_sizes; (void)n_in;
  const float* chem = (const float*)d_in[0];
  const float* gene = (const float*)d_in[1];
  const float *W1[4], *B1[4], *W2[4], *B2[4];
  const int *SRC[4], *DST[4];
  // etype order: 0=ch2ge, 1=ge2ch, 2=ch2ch, 3=ge2ge
  for (int t = 0; t < 4; t++) {
    W1[t]  = (const float*)d_in[2 + 6 * t];
    B1[t]  = (const float*)d_in[3 + 6 * t];
    W2[t]  = (const float*)d_in[4 + 6 * t];
    B2[t]  = (const float*)d_in[5 + 6 * t];
    SRC[t] = (const int*)d_in[6 + 6 * t];
    DST[t] = (const int*)d_in[7 + 6 * t];
  }

  size_t off_b = 0;
  auto carve = [&](size_t bytes) -> void* {
    void* p = (char*)d_ws + off_b;
    off_b += (bytes + 255) & ~(size_t)255;
    return p;
  };
  const size_t FEAT_B = (size_t)NNODE * DIM * 2;  // 25.6 MB bf16
  unsigned short* xb_chem = (unsigned short*)carve(FEAT_B);
  unsigned short* xb_gene = (unsigned short*)carve(FEAT_B);
  unsigned short* h1_chem = (unsigned short*)carve(FEAT_B);
  unsigned short* h1_gene = (unsigned short*)carve(FEAT_B);
  unsigned short* aggA    = (unsigned short*)carve(FEAT_B);  // pairs+scan matrix aliased here
  unsigned short* aggB    = (unsigned short*)carve(FEAT_B);
  int* S    = (int*)carve(((size_t)NTOT + 1) * 4);
  int* srcs = (int*)carve((size_t)NET * EDGES * 4);
  unsigned short* WTc1 = (unsigned short*)carve((size_t)256 * 512 * 2);
  unsigned short* WTg1 = (unsigned short*)carve((size_t)256 * 512 * 2);
  unsigned short* WTc2 = (unsigned short*)carve((size_t)256 * 512 * 2);
  // aliases inside aggA (dead until after CSR build):
  unsigned int* pairs = (unsigned int*)aggA;                         // 6.4 MB
  int* cntoff = (int*)((char*)aggA + 6400000);                       // NSCAN+1 ints
  int* bsum   = cntoff + (NSCAN + 1);                                // 128 ints

  if (off_b > ws_size) {
    fill_f32<<<(out_size + 255) / 256, 256, 0, stream>>>((float*)d_out, (float)(ws_size >> 20), out_size);
    return;
  }

  int n4 = NNODE * DIM / 4;
  conv_f32_bf16<<<(n4 + 255) / 256, 256, 0, stream>>>(chem, xb_chem, n4);
  conv_f32_bf16<<<(n4 + 255) / 256, 256, 0, stream>>>(gene, xb_gene, n4);
  // stacked W slabs (BK=32, pre-swizzled): c1=(W1[1],W1[2])  g1=(W1[0],W1[3])  c2=(W2[1],W2[2])
  conv_wT32<<<dim3(256, 3), 256, 0, stream>>>(W1[1], W1[2], W1[0], W1[3], W2[1], W2[2],
                                              WTc1, WTg1, WTc2);

  // ---- multi-split CSR build ----
  dim3 cgrid(CPE, 4);
  hist_ms<<<cgrid, 256, 0, stream>>>(DST[0], DST[1], DST[2], DST[3], cntoff);
  int nb1 = (NSCAN + 4095) / 4096;   // 75
  scan_p1<<<nb1, 256, 0, stream>>>(cntoff, bsum, NSCAN);
  scan_p2<<<1, 128, 0, stream>>>(bsum, nb1, cntoff, NSCAN, S);
  scan_p3<<<nb1, 256, 0, stream>>>(cntoff, bsum, NSCAN);
  scatter_ms<<<cgrid, 256, 0, stream>>>(SRC[0], SRC[1], SRC[2], SRC[3],
                                        DST[0], DST[1], DST[2], DST[3], cntoff, pairs);
  bucket_final<<<NBUCK, 256, 0, stream>>>(cntoff, pairs, S, srcs);

  dim3 ggrid2((NNODE + 63) / 64);   // 782 blocks, full-N per block
  int nagg = NNODE / 4;             // 12500 blocks x 4 waves
  // ---- layer 1, dt=chemical: et1 (src gene) + et2 (src chem)
  agg_pair<<<nagg, 256, 0, stream>>>(S, srcs, xb_gene, 1, aggA, xb_chem, 2, aggB);
  gemm512<0><<<ggrid2, 256, 0, stream>>>(aggA, aggB, WTc1, B1[1], B1[2], S, 1, 2, h1_chem, NNODE);
  // ---- layer 1, dt=gene: et0 (src chem) + et3 (src gene)
  agg_pair<<<nagg, 256, 0, stream>>>(S, srcs, xb_chem, 0, aggA, xb_gene, 3, aggB);
  gemm512<0><<<ggrid2, 256, 0, stream>>>(aggA, aggB, WTg1, B1[0], B1[3], S, 0, 3, h1_gene, NNODE);
  // ---- layer 2, dt=chemical only
  agg_pair<<<nagg, 256, 0, stream>>>(S, srcs, h1_gene, 1, aggA, h1_chem, 2, aggB);
  gemm512<1><<<ggrid2, 256, 0, stream>>>(aggA, aggB, WTc2, B2[1], B2[2], S, 1, 2, d_out, NNODE);
}

// Round 17
// 398.975 us; speedup vs baseline: 1.0065x; 1.0065x over previous
//
#include <hip/hip_runtime.h>
#include <hip/hip_bf16.h>

#define NNODE 50000
#define DIM   256
#define EDGES 400000
#define NET   4
#define NTOT  (NET * NNODE)          // 200000
#define BSH   7
#define NBUCK ((NTOT + 127) >> BSH)  // 1563
#define EPB2  8192                   // edges per chunk
#define CPE   49                     // chunks per etype (49*8192 >= 400000)
#define NBLKT (CPE * NET)            // 196 chunk-blocks total
#define NSCAN (NBUCK * NBLKT)        // 306348

#define AS1 __attribute__((address_space(1)))
#define AS3 __attribute__((address_space(3)))

typedef __attribute__((ext_vector_type(8))) __bf16 bf16x8;
typedef __attribute__((ext_vector_type(4))) float f32x4;
typedef __attribute__((ext_vector_type(4))) unsigned short u16x4;
typedef __attribute__((ext_vector_type(8))) unsigned short u16x8;

__device__ __forceinline__ float bf2f(unsigned short u) {
  unsigned int x = ((unsigned int)u) << 16;
  return __builtin_bit_cast(float, x);
}
__device__ __forceinline__ unsigned short f2bf(float f) {
  __hip_bfloat16 h = __float2bfloat16(f);   // RTNE
  return __builtin_bit_cast(unsigned short, h);
}

__global__ void conv_f32_bf16(const float* __restrict__ in, unsigned short* __restrict__ out, int n4) {
  int i = blockIdx.x * blockDim.x + threadIdx.x;
  if (i >= n4) return;
  f32x4 v = reinterpret_cast<const f32x4*>(in)[i];
  u16x4 o;
  o[0] = f2bf(v[0]); o[1] = f2bf(v[1]); o[2] = f2bf(v[2]); o[3] = f2bf(v[3]);
  reinterpret_cast<u16x4*>(out)[i] = o;
}

// Stacked-K weights in BK=32-chunk-major PRE-SWIZZLED layout (proven rounds 13-15):
// logical (row n, k<512) -> T[ck*8192 + n*32 + ((kg^(n&3))<<3) + j]  (ushort units),
// ck = k>>5 (A-half: slabs 0..7) / 8+(k>>5) (B-half: slabs 8..15), kg=(k>>3)&3,
// j=k&7. Each slab is a contiguous 16KB chunk (fully sequential staging); the
// kg-XOR pre-swizzle makes ds_read_b128 B-frags bank-friendly with a LINEAR LDS
// image (rule 21: swizzle source, linear dest).
__global__ void conv_wT32(const float* __restrict__ a0, const float* __restrict__ b0,
                          const float* __restrict__ a1, const float* __restrict__ b1,
                          const float* __restrict__ a2, const float* __restrict__ b2,
                          unsigned short* __restrict__ t0, unsigned short* __restrict__ t1,
                          unsigned short* __restrict__ t2) {
  int m = blockIdx.y;
  const float* A = (m == 0) ? a0 : (m == 1) ? a1 : a2;
  const float* B = (m == 0) ? b0 : (m == 1) ? b1 : b2;
  unsigned short* T = (m == 0) ? t0 : (m == 1) ? t1 : t2;
  int n = blockIdx.x, k = threadIdx.x;   // 256 threads, k in [0,256)
  int kg = (k >> 3) & 3, j = k & 7;
  int sw = ((kg ^ (n & 3)) << 3) + j;
  T[(k >> 5) * 8192 + n * 32 + sw]       = f2bf(A[k * 256 + n]);   // A-half: ck 0..7
  T[(8 + (k >> 5)) * 8192 + n * 32 + sw] = f2bf(B[k * 256 + n]);   // B-half: ck 8..15
}

__global__ void fill_f32(float* __restrict__ p, float v, int n) {
  int i = blockIdx.x * blockDim.x + threadIdx.x;
  if (i < n) p[i] = v;
}

// ---- multi-split CSR build: no per-edge global atomics (proven rounds 3-15) ----
__global__ void hist_ms(const int* __restrict__ d0, const int* __restrict__ d1,
                        const int* __restrict__ d2, const int* __restrict__ d3,
                        int* __restrict__ cnt) {
  __shared__ int h[NBUCK];
  for (int i = threadIdx.x; i < NBUCK; i += 256) h[i] = 0;
  __syncthreads();
  int t = blockIdx.y, cx = blockIdx.x;
  const int* dp = (t == 0) ? d0 : (t == 1) ? d1 : (t == 2) ? d2 : d3;
  int base = cx * EPB2;
  int lim = base + EPB2; if (lim > EDGES) lim = EDGES;
  for (int i = base + threadIdx.x; i < lim; i += 256)
    atomicAdd(&h[(t * NNODE + dp[i]) >> BSH], 1);
  __syncthreads();
  int blk = t * CPE + cx;
  for (int i = threadIdx.x; i < NBUCK; i += 256)
    cnt[i * NBLKT + blk] = h[i];
}

__global__ void scan_p1(const int* __restrict__ data, int* __restrict__ bsum, int n) {
  __shared__ int red[256];
  int base = blockIdx.x * 4096;
  int s = 0;
  #pragma unroll
  for (int j = 0; j < 16; j++) {
    int idx = base + j * 256 + threadIdx.x;
    s += (idx < n) ? data[idx] : 0;
  }
  red[threadIdx.x] = s;
  __syncthreads();
  for (int o = 128; o > 0; o >>= 1) {
    if (threadIdx.x < o) red[threadIdx.x] += red[threadIdx.x + o];
    __syncthreads();
  }
  if (threadIdx.x == 0) bsum[blockIdx.x] = red[0];
}

__global__ void scan_p2(int* __restrict__ bsum, int nb, int* __restrict__ off, int nscan,
                        int* __restrict__ S) {
  __shared__ int sh[128];
  int tid = threadIdx.x;
  int v = (tid < nb) ? bsum[tid] : 0;
  sh[tid] = v;
  __syncthreads();
  for (int o = 1; o < 128; o <<= 1) {
    int a = (tid >= o) ? sh[tid - o] : 0;
    __syncthreads();
    sh[tid] += a;
    __syncthreads();
  }
  if (tid < nb) bsum[tid] = sh[tid] - v;   // exclusive block bases
  if (tid == 0) { off[nscan] = sh[127]; S[NTOT] = sh[127]; }
}

__global__ void scan_p3(int* __restrict__ data, const int* __restrict__ bsum, int n) {
  __shared__ int sh[256];
  int tid = threadIdx.x;
  int base = blockIdx.x * 4096 + tid * 16;
  int vals[16];
  int s = 0;
  #pragma unroll
  for (int j = 0; j < 16; j++) {
    vals[j] = (base + j < n) ? data[base + j] : 0;
    s += vals[j];
  }
  sh[tid] = s;
  __syncthreads();
  for (int o = 1; o < 256; o <<= 1) {
    int a = (tid >= o) ? sh[tid - o] : 0;
    __syncthreads();
    sh[tid] += a;
    __syncthreads();
  }
  int run = bsum[blockIdx.x] + sh[tid] - s;
  #pragma unroll
  for (int j = 0; j < 16; j++) {
    if (base + j < n) { data[base + j] = run; run += vals[j]; }
  }
}

__global__ void scatter_ms(const int* __restrict__ s0, const int* __restrict__ s1,
                           const int* __restrict__ s2, const int* __restrict__ s3,
                           const int* __restrict__ d0, const int* __restrict__ d1,
                           const int* __restrict__ d2, const int* __restrict__ d3,
                           const int* __restrict__ off, unsigned int* __restrict__ pairs) {
  __shared__ int cur[NBUCK];
  int t = blockIdx.y, cx = blockIdx.x;
  int blk = t * CPE + cx;
  for (int i = threadIdx.x; i < NBUCK; i += 256)
    cur[i] = off[i * NBLKT + blk];
  __syncthreads();
  const int* sp = (t == 0) ? s0 : (t == 1) ? s1 : (t == 2) ? s2 : s3;
  const int* dp = (t == 0) ? d0 : (t == 1) ? d1 : (t == 2) ? d2 : d3;
  int base = cx * EPB2;
  int lim = base + EPB2; if (lim > EDGES) lim = EDGES;
  for (int i = base + threadIdx.x; i < lim; i += 256) {
    int key = t * NNODE + dp[i];
    int slot = atomicAdd(&cur[key >> BSH], 1);
    pairs[slot] = ((unsigned int)(key & 127) << 16) | (unsigned int)sp[i];
  }
}

__global__ void bucket_final(const int* __restrict__ off, const unsigned int* __restrict__ pairs,
                             int* __restrict__ S, int* __restrict__ srcs) {
  __shared__ int lcnt[128];
  __shared__ int loff[128];
  int b = blockIdx.x;
  int tid = threadIdx.x;
  int beg = off[b * NBLKT], end = off[(b + 1) * NBLKT];
  if (tid < 128) lcnt[tid] = 0;
  __syncthreads();
  for (int e = beg + tid; e < end; e += 256)
    atomicAdd(&lcnt[pairs[e] >> 16], 1);
  __syncthreads();
  int c = (tid < 128) ? lcnt[tid] : 0;
  if (tid < 128) loff[tid] = c;
  __syncthreads();
  for (int o = 1; o < 128; o <<= 1) {
    int a = (tid < 128 && tid >= o) ? loff[tid - o] : 0;
    __syncthreads();
    if (tid < 128) loff[tid] += a;
    __syncthreads();
  }
  if (tid < 128) {
    int ex = loff[tid] - c;
    int key = (b << BSH) + tid;
    if (key < NTOT) S[key] = beg + ex;
    lcnt[tid] = ex;                   // running cursor
  }
  __syncthreads();
  for (int e = beg + tid; e < end; e += 256) {
    unsigned int p = pairs[e];
    int lk = p >> 16;
    int slot = beg + atomicAdd(&lcnt[lk], 1);
    srcs[slot] = (int)(p & 0xFFFFu);
  }
}

// ---- aggregation: mean of src features per (etype, dst). Two etypes fused.
// Output written in the GEMM's BK=32 slab-major pre-swizzled layout:
// elem k of row d -> slab (k>>5), off d*32 + (((k>>3)&3 ^ (d&3))<<3) + (k&7).
#define ACC8(V)                                             \
  { _Pragma("unroll")                                       \
    for (int j = 0; j < 8; j++) acc[j] += bf2f((V)[j]); }

__device__ __forceinline__ void agg_loop(const int* __restrict__ srcs, int e0, int e1,
                                         int half, int l5,
                                         const unsigned short* __restrict__ feat, float* acc) {
  int e = e0 + half;
  u16x8 z = {};
  #define LDK(K) ((e + 2*(K) < e1)                                                    \
      ? *reinterpret_cast<const u16x8*>(feat + (size_t)srcs[e + 2*(K)] * 256 + l5 * 8) \
      : z)
  u16x8 v0 = LDK(0), v1 = LDK(1), v2 = LDK(2), v3 = LDK(3);
  while (e + 8 < e1) {
    u16x8 c0 = v0, c1 = v1, c2 = v2, c3 = v3;
    e += 8;
    v0 = LDK(0); v1 = LDK(1); v2 = LDK(2); v3 = LDK(3);
    ACC8(c0); ACC8(c1); ACC8(c2); ACC8(c3);
  }
  ACC8(v0); ACC8(v1); ACC8(v2); ACC8(v3);   // masked-out slots are zero
  #undef LDK
}

__global__ __launch_bounds__(256) void agg_pair(
    const int* __restrict__ S, const int* __restrict__ srcs,
    const unsigned short* __restrict__ featA, int etA, unsigned short* __restrict__ outA,
    const unsigned short* __restrict__ featB, int etB, unsigned short* __restrict__ outB)
{
  int d = blockIdx.x * 4 + (threadIdx.x >> 6);
  int lane = threadIdx.x & 63;
  int half = lane >> 5, l5 = lane & 31;
  // BK=32 slab-major pre-swizzled output position: lane holds k = l5*8..l5*8+7
  // -> slab l5>>2, seg (l5&3)^(d&3); in ushort units (row = 32 elems).
  size_t obase = ((size_t)(l5 >> 2) * NNODE + d) * 32 + (size_t)(((l5 & 3) ^ (d & 3)) << 3);

  int gA = etA * NNODE + d;
  int a0 = S[gA], a1 = S[gA + 1];
  int gB = etB * NNODE + d;
  int b0 = S[gB], b1 = S[gB + 1];

  {
    float acc[8] = {0,0,0,0,0,0,0,0};
    agg_loop(srcs, a0, a1, half, l5, featA, acc);
    #pragma unroll
    for (int j = 0; j < 8; j++) acc[j] += __shfl_xor(acc[j], 32);
    float dA = (float)(a1 - a0); if (dA < 1.f) dA = 1.f;
    float invA = 1.f / dA;
    if (half == 0) {
      u16x8 o;
      #pragma unroll
      for (int j = 0; j < 8; j++) o[j] = f2bf(acc[j] * invA);
      *reinterpret_cast<u16x8*>(outA + obase) = o;
    }
  }
  {
    float acc[8] = {0,0,0,0,0,0,0,0};
    agg_loop(srcs, b0, b1, half, l5, featB, acc);
    #pragma unroll
    for (int j = 0; j < 8; j++) acc[j] += __shfl_xor(acc[j], 32);
    float dB = (float)(b1 - b0); if (dB < 1.f) dB = 1.f;
    float invB = 1.f / dB;
    if (half == 1) {
      u16x8 o;
      #pragma unroll
      for (int j = 0; j < 8; j++) o[j] = f2bf(acc[j] * invB);
      *reinterpret_cast<u16x8*>(outB + obase) = o;
    }
  }
}

// ---- stacked-K GEMM v10 (round-14 known-good, 399us): BK=32 slabs, 40KB
// double-buffer -> 4 blocks/CU. Sequential slab staging via global_load_lds,
// counted vmcnt (5 loads/stage), raw s_barrier pair per chunk, explicit vmcnt(0)
// epilogue before the last compute. Tile 64 rows x 256 cols, grid 782 = one
// all-resident round at 4 blocks/CU.
// MODE 0: leaky_relu + bf16 row-major out. MODE 1: f32 row-major out.
template<int MODE>
__global__ __launch_bounds__(256, 4) void gemm512(
    const unsigned short* __restrict__ A0, const unsigned short* __restrict__ A1,
    const unsigned short* __restrict__ WTb,
    const float* __restrict__ bA, const float* __restrict__ bB,
    const int* __restrict__ S, int etA, int etB,
    void* __restrict__ outp, int M)
{
  __shared__ char lds[2 * 20480];     // per buffer: A slab 4KB + B slab 16KB
  int tid = threadIdx.x;
  int m0 = blockIdx.x * 64;
  int wave = tid >> 6, lane = tid & 63;
  int wr = wave >> 1, wc = wave & 1;
  int lrow = lane & 15, kgrp = lane >> 4;

  f32x4 acc[2][8];
  #pragma unroll
  for (int a = 0; a < 2; a++)
    #pragma unroll
    for (int b = 0; b < 8; b++) acc[a][b] = (f32x4){0.f, 0.f, 0.f, 0.f};

  auto stage = [&](int ck) {
    char* buf = lds + (ck & 1) * 20480;
    // B slab ck: 16KB contiguous, 4 issues x 4KB
    const char* wsrc = (const char*)WTb + (size_t)ck * 16384 + tid * 16;
    #pragma unroll
    for (int iss = 0; iss < 4; iss++)
      __builtin_amdgcn_global_load_lds(
          (const AS1 unsigned int*)(const void*)(wsrc + iss * 4096),
          (AS3 unsigned int*)(void*)(buf + 4096 + iss * 4096 + tid * 16), 16, 0, 0);
    // A slab rows m0..m0+63: 4KB contiguous, 1 issue
    const char* asrc = (const char*)((ck < 8) ? A0 : A1) +
        (size_t)(ck & 7) * NNODE * 64 + (size_t)m0 * 64 + tid * 16;
    __builtin_amdgcn_global_load_lds(
        (const AS1 unsigned int*)(const void*)asrc,
        (AS3 unsigned int*)(void*)(buf + tid * 16), 16, 0, 0);
  };

  auto compute = [&](int ck) {
    const char* buf = lds + (ck & 1) * 20480;
    bf16x8 a[2];
    #pragma unroll
    for (int mb = 0; mb < 2; mb++) {
      int r = 32 * wr + 16 * mb + lrow;
      a[mb] = *reinterpret_cast<const bf16x8*>(buf + r * 64 + ((kgrp ^ (r & 3)) << 4));
    }
    #pragma unroll
    for (int nb = 0; nb < 8; nb++) {
      int n = 128 * wc + 16 * nb + lrow;
      bf16x8 b = *reinterpret_cast<const bf16x8*>(buf + 4096 + n * 64 + ((kgrp ^ (n & 3)) << 4));
      acc[0][nb] = __builtin_amdgcn_mfma_f32_16x16x32_bf16(a[0], b, acc[0][nb], 0, 0, 0);
      acc[1][nb] = __builtin_amdgcn_mfma_f32_16x16x32_bf16(a[1], b, acc[1][nb], 0, 0, 0);
    }
  };

  stage(0);
  for (int ck = 0; ck < 15; ck++) {
    stage(ck + 1);                                   // queue: 5 old + 5 new
    asm volatile("s_waitcnt vmcnt(5)" ::: "memory"); // retire stage(ck) only
    asm volatile("s_barrier" ::: "memory");          // stage(ck) visible to all
    compute(ck);
    asm volatile("s_barrier" ::: "memory");          // all done reading buf[ck&1]
  }
  asm volatile("s_waitcnt vmcnt(0)" ::: "memory");   // retire stage(15)
  asm volatile("s_barrier" ::: "memory");
  compute(15);

  // C/D layout: col = lane&15, row = (lane>>4)*4 + reg  [verified m89/m91]
  #pragma unroll
  for (int mb = 0; mb < 2; mb++) {
    #pragma unroll
    for (int r = 0; r < 4; r++) {
      int row = m0 + 32 * wr + 16 * mb + kgrp * 4 + r;
      if (row >= M) continue;
      int gA = etA * NNODE + row, gB = etB * NNODE + row;
      bool hA = S[gA + 1] > S[gA];   // deg>0: bias enters only via messages
      bool hB = S[gB + 1] > S[gB];
      #pragma unroll
      for (int nb = 0; nb < 8; nb++) {
        int col = 128 * wc + 16 * nb + lrow;
        float bias = (hA ? bA[col] : 0.f) + (hB ? bB[col] : 0.f);
        float v = acc[mb][nb][r] + bias;
        if (MODE == 0) {
          v = (v > 0.f) ? v : 0.01f * v;
          ((unsigned short*)outp)[(size_t)row * 256 + col] = f2bf(v);
        } else {
          ((float*)outp)[(size_t)row * 256 + col] = v;
        }
      }
    }
  }
}

extern "C" void kernel_launch(void* const* d_in, const int* in_sizes, int n_in,
                              void* d_out, int out_size, void* d_ws, size_t ws_size,
                              hipStream_t stream) {
  (void)in_sizes; (void)n_in;
  const float* chem = (const float*)d_in[0];
  const float* gene = (const float*)d_in[1];
  const float *W1[4], *B1[4], *W2[4], *B2[4];
  const int *SRC[4], *DST[4];
  // etype order: 0=ch2ge, 1=ge2ch, 2=ch2ch, 3=ge2ge
  for (int t = 0; t < 4; t++) {
    W1[t]  = (const float*)d_in[2 + 6 * t];
    B1[t]  = (const float*)d_in[3 + 6 * t];
    W2[t]  = (const float*)d_in[4 + 6 * t];
    B2[t]  = (const float*)d_in[5 + 6 * t];
    SRC[t] = (const int*)d_in[6 + 6 * t];
    DST[t] = (const int*)d_in[7 + 6 * t];
  }

  size_t off_b = 0;
  auto carve = [&](size_t bytes) -> void* {
    void* p = (char*)d_ws + off_b;
    off_b += (bytes + 255) & ~(size_t)255;
    return p;
  };
  const size_t FEAT_B = (size_t)NNODE * DIM * 2;  // 25.6 MB bf16
  unsigned short* xb_chem = (unsigned short*)carve(FEAT_B);
  unsigned short* xb_gene = (unsigned short*)carve(FEAT_B);
  unsigned short* h1_chem = (unsigned short*)carve(FEAT_B);
  unsigned short* h1_gene = (unsigned short*)carve(FEAT_B);
  unsigned short* aggA    = (unsigned short*)carve(FEAT_B);  // pairs+scan matrix aliased here
  unsigned short* aggB    = (unsigned short*)carve(FEAT_B);
  int* S    = (int*)carve(((size_t)NTOT + 1) * 4);
  int* srcs = (int*)carve((size_t)NET * EDGES * 4);
  unsigned short* WTc1 = (unsigned short*)carve((size_t)256 * 512 * 2);
  unsigned short* WTg1 = (unsigned short*)carve((size_t)256 * 512 * 2);
  unsigned short* WTc2 = (unsigned short*)carve((size_t)256 * 512 * 2);
  // aliases inside aggA (dead until after CSR build):
  unsigned int* pairs = (unsigned int*)aggA;                         // 6.4 MB
  int* cntoff = (int*)((char*)aggA + 6400000);                       // NSCAN+1 ints
  int* bsum   = cntoff + (NSCAN + 1);                                // 128 ints

  if (off_b > ws_size) {
    fill_f32<<<(out_size + 255) / 256, 256, 0, stream>>>((float*)d_out, (float)(ws_size >> 20), out_size);
    return;
  }

  int n4 = NNODE * DIM / 4;
  conv_f32_bf16<<<(n4 + 255) / 256, 256, 0, stream>>>(chem, xb_chem, n4);
  conv_f32_bf16<<<(n4 + 255) / 256, 256, 0, stream>>>(gene, xb_gene, n4);
  // stacked W slabs (BK=32, pre-swizzled): c1=(W1[1],W1[2])  g1=(W1[0],W1[3])  c2=(W2[1],W2[2])
  conv_wT32<<<dim3(256, 3), 256, 0, stream>>>(W1[1], W1[2], W1[0], W1[3], W2[1], W2[2],
                                              WTc1, WTg1, WTc2);

  // ---- multi-split CSR build ----
  dim3 cgrid(CPE, 4);
  hist_ms<<<cgrid, 256, 0, stream>>>(DST[0], DST[1], DST[2], DST[3], cntoff);
  int nb1 = (NSCAN + 4095) / 4096;   // 75
  scan_p1<<<nb1, 256, 0, stream>>>(cntoff, bsum, NSCAN);
  scan_p2<<<1, 128, 0, stream>>>(bsum, nb1, cntoff, NSCAN, S);
  scan_p3<<<nb1, 256, 0, stream>>>(cntoff, bsum, NSCAN);
  scatter_ms<<<cgrid, 256, 0, stream>>>(SRC[0], SRC[1], SRC[2], SRC[3],
                                        DST[0], DST[1], DST[2], DST[3], cntoff, pairs);
  bucket_final<<<NBUCK, 256, 0, stream>>>(cntoff, pairs, S, srcs);

  dim3 ggrid2((NNODE + 63) / 64);   // 782 blocks, full-N per block
  int nagg = NNODE / 4;             // 12500 blocks x 4 waves
  // ---- layer 1, dt=chemical: et1 (src gene) + et2 (src chem)
  agg_pair<<<nagg, 256, 0, stream>>>(S, srcs, xb_gene, 1, aggA, xb_chem, 2, aggB);
  gemm512<0><<<ggrid2, 256, 0, stream>>>(aggA, aggB, WTc1, B1[1], B1[2], S, 1, 2, h1_chem, NNODE);
  // ---- layer 1, dt=gene: et0 (src chem) + et3 (src gene)
  agg_pair<<<nagg, 256, 0, stream>>>(S, srcs, xb_chem, 0, aggA, xb_gene, 3, aggB);
  gemm512<0><<<ggrid2, 256, 0, stream>>>(aggA, aggB, WTg1, B1[0], B1[3], S, 0, 3, h1_gene, NNODE);
  // ---- layer 2, dt=chemical only
  agg_pair<<<nagg, 256, 0, stream>>>(S, srcs, h1_gene, 1, aggA, h1_chem, 2, aggB);
  gemm512<1><<<ggrid2, 256, 0, stream>>>(aggA, aggB, WTc2, B2[1], B2[2], S, 1, 2, d_out, NNODE);
}